// Round 1
// baseline (1111.488 us; speedup 1.0000x reference)
//
#include <hip/hip_runtime.h>
#include <cstddef>

#define BB 8
#define CC 512
#define LL 2048
#define TT 64

// ---------------------------------------------------------------------------
// K1: Q = W1 @ X, K = W2 @ X   (per batch: (64x512)@(512x2048) -> (64x2048))
// grid (L/64, B), block 256. Each block: all 64 t for a 64-wide l tile.
// ---------------------------------------------------------------------------
__global__ __launch_bounds__(256) void qk_kernel(
    const float* __restrict__ x, const float* __restrict__ W1,
    const float* __restrict__ W2, float* __restrict__ Qg, float* __restrict__ Kg)
{
    __shared__ float Xs[64][65];   // [c_chunk][l]
    __shared__ float W1s[64][66];  // [t][c_chunk], pad 66 keeps float2 8B-aligned
    __shared__ float W2s[64][66];
    const int b  = blockIdx.y;
    const int l0 = blockIdx.x * 64;
    const int tid = threadIdx.x;
    const int l = tid & 63;
    const int g = tid >> 6;        // 0..3, wave-uniform
    const float* xb = x + (size_t)b * CC * LL;

    float qa[16], ka[16];
#pragma unroll
    for (int k = 0; k < 16; ++k) { qa[k] = 0.f; ka[k] = 0.f; }

    for (int c0 = 0; c0 < CC; c0 += 64) {
        __syncthreads();
#pragma unroll
        for (int r = 0; r < 16; ++r) {
            int row = r * 4 + g;
            Xs[row][l]  = xb[(size_t)(c0 + row) * LL + l0 + l];
            W1s[row][l] = W1[(size_t)row * CC + c0 + l];
            W2s[row][l] = W2[(size_t)row * CC + c0 + l];
        }
        __syncthreads();
        for (int cc = 0; cc < 64; cc += 2) {
            float xv0 = Xs[cc][l];
            float xv1 = Xs[cc + 1][l];
#pragma unroll
            for (int k = 0; k < 16; ++k) {
                float2 w1 = *(const float2*)&W1s[g * 16 + k][cc];  // wave-broadcast
                float2 w2 = *(const float2*)&W2s[g * 16 + k][cc];
                qa[k] += w1.x * xv0 + w1.y * xv1;
                ka[k] += w2.x * xv0 + w2.y * xv1;
            }
        }
    }
#pragma unroll
    for (int k = 0; k < 16; ++k) {
        Qg[((size_t)b * TT + g * 16 + k) * LL + l0 + l] = qa[k];
        Kg[((size_t)b * TT + g * 16 + k) * LL + l0 + l] = ka[k];
    }
}

// ---------------------------------------------------------------------------
// K2: per-row softmax stats. M[b,l] = max_m S[l,m], Z[b,l] = sum_m exp(S-M).
// S recomputed on the fly from Q,K. grid (L/64, B), block 256.
// Thread: 4 rows x 4 cols of each 64x64 S tile (float4 LDS reads).
// ---------------------------------------------------------------------------
__global__ __launch_bounds__(256) void mz_kernel(
    const float* __restrict__ Qg, const float* __restrict__ Kg,
    float* __restrict__ Mg, float* __restrict__ Zg)
{
    __shared__ float Qs[64 * 68];  // [t*68 + r]  (68: float4-aligned, low conflicts)
    __shared__ float Ks[64 * 68];  // [t*68 + i]
    const int b  = blockIdx.y;
    const int l0 = blockIdx.x * 64;
    const int tid = threadIdx.x;
    const int rgrp = tid >> 4;   // 0..15 -> rows rgrp*4+rr
    const int igrp = tid & 15;   // cols igrp*4+ii

    for (int idx = tid; idx < 4096; idx += 256) {
        int t = idx >> 6, r = idx & 63;
        Qs[t * 68 + r] = Qg[((size_t)b * TT + t) * LL + l0 + r];
    }
    float m[4], z[4];
#pragma unroll
    for (int rr = 0; rr < 4; ++rr) { m[rr] = -3.0e38f; z[rr] = 0.f; }

    for (int i0 = 0; i0 < LL; i0 += 64) {
        __syncthreads();
        for (int idx = tid; idx < 4096; idx += 256) {
            int t = idx >> 6, ii = idx & 63;
            Ks[t * 68 + ii] = Kg[((size_t)b * TT + t) * LL + i0 + ii];
        }
        __syncthreads();
        float s[4][4];
#pragma unroll
        for (int rr = 0; rr < 4; ++rr)
#pragma unroll
            for (int ii = 0; ii < 4; ++ii) s[rr][ii] = 0.f;
        for (int t = 0; t < 64; ++t) {
            float4 qv = *(const float4*)&Qs[t * 68 + rgrp * 4];
            float4 kv = *(const float4*)&Ks[t * 68 + igrp * 4];
            float qa[4] = {qv.x, qv.y, qv.z, qv.w};
            float ka[4] = {kv.x, kv.y, kv.z, kv.w};
#pragma unroll
            for (int rr = 0; rr < 4; ++rr)
#pragma unroll
                for (int ii = 0; ii < 4; ++ii) s[rr][ii] += qa[rr] * ka[ii];
        }
#pragma unroll
        for (int rr = 0; rr < 4; ++rr) {
            float mt = fmaxf(fmaxf(s[rr][0], s[rr][1]), fmaxf(s[rr][2], s[rr][3]));
            float mn = fmaxf(m[rr], mt);
            float zt = __expf(s[rr][0] - mn) + __expf(s[rr][1] - mn) +
                       __expf(s[rr][2] - mn) + __expf(s[rr][3] - mn);
            z[rr] = z[rr] * __expf(m[rr] - mn) + zt;
            m[rr] = mn;
        }
    }
    // combine across the 16 threads (consecutive lanes) sharing each row group
#pragma unroll
    for (int off = 1; off < 16; off <<= 1) {
#pragma unroll
        for (int rr = 0; rr < 4; ++rr) {
            float mo = __shfl_xor(m[rr], off);
            float zo = __shfl_xor(z[rr], off);
            float mn = fmaxf(m[rr], mo);
            z[rr] = z[rr] * __expf(m[rr] - mn) + zo * __expf(mo - mn);
            m[rr] = mn;
        }
    }
    if (igrp == 0) {
#pragma unroll
        for (int rr = 0; rr < 4; ++rr) {
            Mg[(size_t)b * LL + l0 + rgrp * 4 + rr] = m[rr];
            Zg[(size_t)b * LL + l0 + rgrp * 4 + rr] = z[rr];
        }
    }
}

// ---------------------------------------------------------------------------
// K3: out[b,c,j] = x[b,c,j] + g * sum_i P[j,i] * x[b,c,i],
//     P[j,i] = exp(S[j,i]-M[j])/Z[j], S recomputed from Q,K.
// grid (L/64 j-tiles, C/256 csplit, B), block 256.
// Phase A: 64x64 S tile -> normalized P (transposed in LDS).
// Phase B: 8x8 per-thread register tile accumulation (strided cols).
// ---------------------------------------------------------------------------
__global__ __launch_bounds__(256) void out_kernel(
    const float* __restrict__ x, const float* __restrict__ Qg,
    const float* __restrict__ Kg, const float* __restrict__ Mg,
    const float* __restrict__ Zg, const float* __restrict__ gamma,
    float* __restrict__ out)
{
    __shared__ float smem[13184];          // 52.7 KB
    float* Qs  = smem;                     // [t*68 + r]     (4352)
    float* Ps  = smem + 4352;              // [i*68 + r]     (4352)  P transposed
    float* KXs = smem + 8704;              // K:[t*68+i] / X:[c*17+ii]  (4352)
    float* Ms  = smem + 13056;             // 64
    float* Zs  = smem + 13120;             // 64

    const int b  = blockIdx.z;
    const int l0 = blockIdx.x * 64;        // j-rows of P
    const int c0 = blockIdx.y * 256;       // c columns handled by this block
    const int tid = threadIdx.x;
    const int rgrpA = tid >> 4;            // phase A: rows rgrpA*4+rr
    const int igrp  = tid & 15;            //          cols igrp*4+ii
    const int rgrpB = tid >> 5;            // phase B: rows rgrpB*8+rr
    const int cgrp  = tid & 31;            //          cols cgrp + cc*32
    const float g = gamma[0];
    const float* xb = x + (size_t)b * CC * LL;

    for (int idx = tid; idx < 4096; idx += 256) {
        int t = idx >> 6, r = idx & 63;
        Qs[t * 68 + r] = Qg[((size_t)b * TT + t) * LL + l0 + r];
    }
    if (tid < 64) {
        Ms[tid] = Mg[(size_t)b * LL + l0 + tid];
        Zs[tid] = Zg[(size_t)b * LL + l0 + tid];
    }
    __syncthreads();
    float mrow[4], zirow[4];               // loop-invariant per thread
#pragma unroll
    for (int rr = 0; rr < 4; ++rr) {
        mrow[rr]  = Ms[rgrpA * 4 + rr];
        zirow[rr] = 1.0f / Zs[rgrpA * 4 + rr];
    }

    float acc[8][8];
#pragma unroll
    for (int rr = 0; rr < 8; ++rr)
#pragma unroll
        for (int cc = 0; cc < 8; ++cc) acc[rr][cc] = 0.f;

    for (int i0 = 0; i0 < LL; i0 += 64) {
        // ---- phase A: load K tile, compute S, emit normalized P^T ----
        for (int idx = tid; idx < 4096; idx += 256) {
            int t = idx >> 6, ii = idx & 63;
            KXs[t * 68 + ii] = Kg[((size_t)b * TT + t) * LL + i0 + ii];
        }
        __syncthreads();
        float s[4][4];
#pragma unroll
        for (int rr = 0; rr < 4; ++rr)
#pragma unroll
            for (int ii = 0; ii < 4; ++ii) s[rr][ii] = 0.f;
        for (int t = 0; t < 64; ++t) {
            float4 qv = *(const float4*)&Qs[t * 68 + rgrpA * 4];
            float4 kv = *(const float4*)&KXs[t * 68 + igrp * 4];
            float qa[4] = {qv.x, qv.y, qv.z, qv.w};
            float ka[4] = {kv.x, kv.y, kv.z, kv.w};
#pragma unroll
            for (int rr = 0; rr < 4; ++rr)
#pragma unroll
                for (int ii = 0; ii < 4; ++ii) s[rr][ii] += qa[rr] * ka[ii];
        }
#pragma unroll
        for (int rr = 0; rr < 4; ++rr)
#pragma unroll
            for (int ii = 0; ii < 4; ++ii) {
                float p = __expf(s[rr][ii] - mrow[rr]) * zirow[rr];
                Ps[(igrp * 4 + ii) * 68 + rgrpA * 4 + rr] = p;
            }
        __syncthreads();

        // ---- phase B: acc[j, c] += P[j,i] * X[c,i], 16-i subchunks ----
        for (int sub = 0; sub < 4; ++sub) {
            for (int idx = tid; idx < 4096; idx += 256) {
                int c = idx >> 4, ii = idx & 15;
                KXs[c * 17 + ii] = xb[(size_t)(c0 + c) * LL + i0 + sub * 16 + ii];
            }
            __syncthreads();
#pragma unroll 4
            for (int ii = 0; ii < 16; ++ii) {
                int i = sub * 16 + ii;
                float4 p0 = *(const float4*)&Ps[i * 68 + rgrpB * 8];
                float4 p1 = *(const float4*)&Ps[i * 68 + rgrpB * 8 + 4];
                float pv[8] = {p0.x, p0.y, p0.z, p0.w, p1.x, p1.y, p1.z, p1.w};
                float xv[8];
#pragma unroll
                for (int cc = 0; cc < 8; ++cc)
                    xv[cc] = KXs[(cgrp + cc * 32) * 17 + ii];  // conflict-free (17 odd)
#pragma unroll
                for (int rr = 0; rr < 8; ++rr)
#pragma unroll
                    for (int cc = 0; cc < 8; ++cc) acc[rr][cc] += pv[rr] * xv[cc];
            }
            __syncthreads();
        }
    }

    // ---- epilogue: transpose-stage through LDS, coalesced write + residual ----
    float* stage = smem;                   // 128*65 floats, Qs/Ps dead now
    for (int h = 0; h < 2; ++h) {
#pragma unroll
        for (int cl = 0; cl < 4; ++cl)
#pragma unroll
            for (int rr = 0; rr < 8; ++rr)
                stage[(cgrp + cl * 32) * 65 + rgrpB * 8 + rr] = acc[rr][h * 4 + cl];
        __syncthreads();
        for (int idx = tid; idx < 8192; idx += 256) {
            int c = idx >> 6, j = idx & 63;
            size_t go = (size_t)b * CC * LL + (size_t)(c0 + h * 128 + c) * LL + l0 + j;
            out[go] = x[go] + g * stage[c * 65 + j];
        }
        __syncthreads();
    }
}

// ---------------------------------------------------------------------------
extern "C" void kernel_launch(void* const* d_in, const int* in_sizes, int n_in,
                              void* d_out, int out_size, void* d_ws, size_t ws_size,
                              hipStream_t stream)
{
    const float* x     = (const float*)d_in[0];
    const float* W1    = (const float*)d_in[1];
    const float* W2    = (const float*)d_in[2];
    const float* gamma = (const float*)d_in[3];
    // d_in[4] = ranges (unused, always 0)
    float* out = (float*)d_out;

    float* Qw = (float*)d_ws;                       // B*T*L = 1,048,576 floats
    float* Kw = Qw + (size_t)BB * TT * LL;          // B*T*L
    float* Mw = Kw + (size_t)BB * TT * LL;          // B*L
    float* Zw = Mw + (size_t)BB * LL;               // B*L   (total ~8.2 MB)

    qk_kernel <<<dim3(LL / 64, BB),    256, 0, stream>>>(x, W1, W2, Qw, Kw);
    mz_kernel <<<dim3(LL / 64, BB),    256, 0, stream>>>(Qw, Kw, Mw, Zw);
    out_kernel<<<dim3(LL / 64, 2, BB), 256, 0, stream>>>(x, Qw, Kw, Mw, Zw, gamma, out);
}

// Round 2
// 354.647 us; speedup vs baseline: 3.1341x; 3.1341x over previous
//
#include <hip/hip_runtime.h>
#include <cstddef>

#define BB 8
#define CC 512
#define LL 2048
#define TT 64

typedef short short8 __attribute__((ext_vector_type(8)));
typedef float floatx4 __attribute__((ext_vector_type(4)));
typedef unsigned short b16u;

static __device__ __forceinline__ b16u f2bf(float f) {
    unsigned int u = __float_as_uint(f);
    u += 0x7fffu + ((u >> 16) & 1u);          // round-to-nearest-even
    return (b16u)(u >> 16);
}

#define MFMA16(a, b, c) __builtin_amdgcn_mfma_f32_16x16x32_bf16((a), (b), (c), 0, 0, 0)

// ---------------------------------------------------------------------------
// K0: X (b,c,l) fp32 -> XT (b, l/64, c, 64) bf16.  16B out unit per step.
// ---------------------------------------------------------------------------
__global__ __launch_bounds__(256) void cvt_kernel(
    const float* __restrict__ x, b16u* __restrict__ XT)
{
    unsigned t0 = blockIdx.x * 256 + threadIdx.x;
#pragma unroll
    for (int p = 0; p < 4; ++p) {
        unsigned u = t0 + p * 262144u;        // u indexes 8-elem groups
        int s  = u & 7;
        int c  = (u >> 3) & 511;
        int lt = (u >> 12) & 31;
        int b  = u >> 17;
        const float* src = x + (size_t)(b * 512 + c) * 2048 + lt * 64 + s * 8;
        float4 v0 = *(const float4*)src;
        float4 v1 = *(const float4*)(src + 4);
        uint4 w;
        w.x = (unsigned)f2bf(v0.x) | ((unsigned)f2bf(v0.y) << 16);
        w.y = (unsigned)f2bf(v0.z) | ((unsigned)f2bf(v0.w) << 16);
        w.z = (unsigned)f2bf(v1.x) | ((unsigned)f2bf(v1.y) << 16);
        w.w = (unsigned)f2bf(v1.z) | ((unsigned)f2bf(v1.w) << 16);
        *(uint4*)(XT + (size_t)u * 8) = w;
    }
}

// ---------------------------------------------------------------------------
// K1: Q = W1 @ X, K = W2 @ X  (fp32 VALU), output TRANSPOSED bf16 (b, l, t).
// grid (L/64, B), block 256.
// ---------------------------------------------------------------------------
__global__ __launch_bounds__(256) void qk_kernel(
    const float* __restrict__ x, const float* __restrict__ W1,
    const float* __restrict__ W2, b16u* __restrict__ Qt, b16u* __restrict__ Kt)
{
    __shared__ float Xs[64][65];
    __shared__ float W1s[64][66];
    __shared__ float W2s[64][66];
    const int b  = blockIdx.y;
    const int l0 = blockIdx.x * 64;
    const int tid = threadIdx.x;
    const int l = tid & 63;
    const int g = tid >> 6;
    const float* xb = x + (size_t)b * CC * LL;

    float qa[16], ka[16];
#pragma unroll
    for (int k = 0; k < 16; ++k) { qa[k] = 0.f; ka[k] = 0.f; }

    for (int c0 = 0; c0 < CC; c0 += 64) {
        __syncthreads();
#pragma unroll
        for (int r = 0; r < 16; ++r) {
            int row = r * 4 + g;
            Xs[row][l]  = xb[(size_t)(c0 + row) * LL + l0 + l];
            W1s[row][l] = W1[(size_t)row * CC + c0 + l];
            W2s[row][l] = W2[(size_t)row * CC + c0 + l];
        }
        __syncthreads();
        for (int cc = 0; cc < 64; cc += 2) {
            float xv0 = Xs[cc][l];
            float xv1 = Xs[cc + 1][l];
#pragma unroll
            for (int k = 0; k < 16; ++k) {
                float2 w1 = *(const float2*)&W1s[g * 16 + k][cc];
                float2 w2 = *(const float2*)&W2s[g * 16 + k][cc];
                qa[k] += w1.x * xv0 + w1.y * xv1;
                ka[k] += w2.x * xv0 + w2.y * xv1;
            }
        }
    }
    b16u* qdst = Qt + ((size_t)(b * 2048) + l0 + l) * 64 + g * 16;
    b16u* kdst = Kt + ((size_t)(b * 2048) + l0 + l) * 64 + g * 16;
    uint4 wq0, wq1, wk0, wk1;
    unsigned* pq0 = (unsigned*)&wq0; unsigned* pq1 = (unsigned*)&wq1;
    unsigned* pk0 = (unsigned*)&wk0; unsigned* pk1 = (unsigned*)&wk1;
#pragma unroll
    for (int j = 0; j < 4; ++j) {
        pq0[j] = (unsigned)f2bf(qa[2*j])   | ((unsigned)f2bf(qa[2*j+1]) << 16);
        pq1[j] = (unsigned)f2bf(qa[8+2*j]) | ((unsigned)f2bf(qa[9+2*j]) << 16);
        pk0[j] = (unsigned)f2bf(ka[2*j])   | ((unsigned)f2bf(ka[2*j+1]) << 16);
        pk1[j] = (unsigned)f2bf(ka[8+2*j]) | ((unsigned)f2bf(ka[9+2*j]) << 16);
    }
    *(uint4*)qdst = wq0; *(uint4*)(qdst + 8) = wq1;
    *(uint4*)kdst = wk0; *(uint4*)(kdst + 8) = wk1;
}

// ---------------------------------------------------------------------------
// K2: softmax stats via MFMA.  grid (L/64, B), block 256 (4 waves x 16 j-rows).
// ---------------------------------------------------------------------------
__global__ __launch_bounds__(256) void mz_kernel(
    const b16u* __restrict__ Qt, const b16u* __restrict__ Kt,
    float* __restrict__ Mg, float* __restrict__ Zg)
{
    __shared__ b16u Qs[64 * 72];
    __shared__ b16u Ks[64 * 72];
    const int b  = blockIdx.y;
    const int l0 = blockIdx.x * 64;
    const int tid = threadIdx.x;
    const int lane = tid & 63;
    const int w = tid >> 6;
    const int n16 = lane & 15;
    const int q = lane >> 4;
    const int jw = w * 16;

#pragma unroll
    for (int p = 0; p < 2; ++p) {
        int u = tid + p * 256, j = u >> 3, s = u & 7;
        *(uint4*)&Qs[j * 72 + s * 8] =
            *(const uint4*)(Qt + ((size_t)(b * 2048) + l0 + j) * 64 + s * 8);
    }
    float m[4], z[4];
#pragma unroll
    for (int r = 0; r < 4; ++r) { m[r] = -3.0e38f; z[r] = 0.f; }

    for (int i0 = 0; i0 < LL; i0 += 64) {
        __syncthreads();
#pragma unroll
        for (int p = 0; p < 2; ++p) {
            int u = tid + p * 256, i = u >> 3, s = u & 7;
            *(uint4*)&Ks[i * 72 + s * 8] =
                *(const uint4*)(Kt + ((size_t)(b * 2048) + i0 + i) * 64 + s * 8);
        }
        __syncthreads();
        floatx4 sacc[4];
#pragma unroll
        for (int ns = 0; ns < 4; ++ns) sacc[ns] = (floatx4){0.f, 0.f, 0.f, 0.f};
#pragma unroll
        for (int kc = 0; kc < 2; ++kc) {
            short8 a = *(const short8*)&Qs[(jw + n16) * 72 + kc * 32 + q * 8];
#pragma unroll
            for (int ns = 0; ns < 4; ++ns) {
                short8 bb = *(const short8*)&Ks[(ns * 16 + n16) * 72 + kc * 32 + q * 8];
                sacc[ns] = MFMA16(a, bb, sacc[ns]);
            }
        }
#pragma unroll
        for (int r = 0; r < 4; ++r) {
            float tmax = fmaxf(fmaxf(sacc[0][r], sacc[1][r]),
                               fmaxf(sacc[2][r], sacc[3][r]));
#pragma unroll
            for (int off = 1; off < 16; off <<= 1)
                tmax = fmaxf(tmax, __shfl_xor(tmax, off));
            float mn = fmaxf(m[r], tmax);
            float es = __expf(sacc[0][r] - mn) + __expf(sacc[1][r] - mn) +
                       __expf(sacc[2][r] - mn) + __expf(sacc[3][r] - mn);
#pragma unroll
            for (int off = 1; off < 16; off <<= 1)
                es += __shfl_xor(es, off);
            z[r] = z[r] * __expf(m[r] - mn) + es;
            m[r] = mn;
        }
    }
    if (n16 == 0) {
#pragma unroll
        for (int r = 0; r < 4; ++r) {
            int row = jw + q * 4 + r;
            Mg[(size_t)b * LL + l0 + row] = m[r];
            Zg[(size_t)b * LL + l0 + row] = z[r];
        }
    }
}

// ---------------------------------------------------------------------------
// K3: out[b,c,j] = x[b,c,j] + g * sum_i P[j,i] * X[c,i]  via MFMA.
// grid (L/64, C/256, B), block 256.  Per wave: 64c x 64j output strip.
// ---------------------------------------------------------------------------
__global__ __launch_bounds__(256, 2) void out_kernel(
    const float* __restrict__ x, const b16u* __restrict__ XT,
    const b16u* __restrict__ Qt, const b16u* __restrict__ Kt,
    const float* __restrict__ Mg, const float* __restrict__ Zg,
    const float* __restrict__ gamma, float* __restrict__ out)
{
    __shared__ __align__(16) char smem_raw[65024];
    b16u* Qs = (b16u*)smem_raw;            // 64*72  sh  (9216 B)
    b16u* Ks = Qs + 4608;                  // 64*72  sh  (9216 B)
    b16u* Ps = Ks + 4608;                  // 64*72  sh  (9216 B)
    b16u* Xs = Ps + 4608;                  // 256*72 sh  (36864 B)
    float* Ms = (float*)(Xs + 18432);      // 64 f
    float* Zs = Ms + 64;                   // 64 f

    const int b  = blockIdx.z;
    const int l0 = blockIdx.x * 64;
    const int c0 = blockIdx.y * 256;
    const int tid = threadIdx.x;
    const int lane = tid & 63;
    const int w = tid >> 6;
    const int n16 = lane & 15;
    const int q = lane >> 4;
    const int jw = w * 16;
    const float g = gamma[0];

#pragma unroll
    for (int p = 0; p < 2; ++p) {
        int u = tid + p * 256, j = u >> 3, s = u & 7;
        *(uint4*)&Qs[j * 72 + s * 8] =
            *(const uint4*)(Qt + ((size_t)(b * 2048) + l0 + j) * 64 + s * 8);
    }
    if (tid < 64) {
        Ms[tid] = Mg[(size_t)b * LL + l0 + tid];
        Zs[tid] = Zg[(size_t)b * LL + l0 + tid];
    }
    __syncthreads();
    float mrow[4], zirow[4];
#pragma unroll
    for (int r = 0; r < 4; ++r) {
        mrow[r]  = Ms[jw + q * 4 + r];
        zirow[r] = 1.0f / Zs[jw + q * 4 + r];
    }

    floatx4 acc[4][4];
#pragma unroll
    for (int mt = 0; mt < 4; ++mt)
#pragma unroll
        for (int nt = 0; nt < 4; ++nt) acc[mt][nt] = (floatx4){0.f, 0.f, 0.f, 0.f};

    for (int i0 = 0; i0 < LL; i0 += 64) {
        const int it = i0 >> 6;
        __syncthreads();                   // prev PV reads done
#pragma unroll
        for (int p = 0; p < 2; ++p) {      // stage K tile (i, t)
            int u = tid + p * 256, i = u >> 3, s = u & 7;
            *(uint4*)&Ks[i * 72 + s * 8] =
                *(const uint4*)(Kt + ((size_t)(b * 2048) + i0 + i) * 64 + s * 8);
        }
        const b16u* xsrc = XT + ((size_t)(b * 32 + it) * 512 + c0) * 64;
#pragma unroll
        for (int p = 0; p < 8; ++p) {      // stage X tile (c, i) — fully coalesced
            int u = tid + p * 256, c = u >> 3, s = u & 7;
            *(uint4*)&Xs[c * 72 + s * 8] = *(const uint4*)(xsrc + u * 8);
        }
        __syncthreads();

        // ---- S phase: 16j x 64i per wave ----
        floatx4 sacc[4];
#pragma unroll
        for (int ns = 0; ns < 4; ++ns) sacc[ns] = (floatx4){0.f, 0.f, 0.f, 0.f};
#pragma unroll
        for (int kc = 0; kc < 2; ++kc) {
            short8 a = *(const short8*)&Qs[(jw + n16) * 72 + kc * 32 + q * 8];
#pragma unroll
            for (int ns = 0; ns < 4; ++ns) {
                short8 bb = *(const short8*)&Ks[(ns * 16 + n16) * 72 + kc * 32 + q * 8];
                sacc[ns] = MFMA16(a, bb, sacc[ns]);
            }
        }
#pragma unroll
        for (int ns = 0; ns < 4; ++ns)
#pragma unroll
            for (int r = 0; r < 4; ++r) {
                float p = __expf(sacc[ns][r] - mrow[r]) * zirow[r];
                Ps[(jw + q * 4 + r) * 72 + ns * 16 + n16] = f2bf(p);
            }
        __syncthreads();

        // ---- PV phase: acc[c-strip w*64 .. +63][64 j] ----
#pragma unroll
        for (int kc = 0; kc < 2; ++kc) {
            short8 af[4], bf[4];
#pragma unroll
            for (int mt = 0; mt < 4; ++mt)
                af[mt] = *(const short8*)&Xs[(w * 64 + mt * 16 + n16) * 72 + kc * 32 + q * 8];
#pragma unroll
            for (int nt = 0; nt < 4; ++nt)
                bf[nt] = *(const short8*)&Ps[(nt * 16 + n16) * 72 + kc * 32 + q * 8];
#pragma unroll
            for (int mt = 0; mt < 4; ++mt)
#pragma unroll
                for (int nt = 0; nt < 4; ++nt)
                    acc[mt][nt] = MFMA16(af[mt], bf[nt], acc[mt][nt]);
        }
    }

    // ---- epilogue: C/D layout (col=lane&15=j, row=q*4+reg=c), 64B segments ----
#pragma unroll
    for (int mt = 0; mt < 4; ++mt)
#pragma unroll
        for (int nt = 0; nt < 4; ++nt) {
            int c = c0 + w * 64 + mt * 16 + q * 4;
            int j = l0 + nt * 16 + n16;
#pragma unroll
            for (int r = 0; r < 4; ++r) {
                size_t go = ((size_t)(b * 512) + c + r) * 2048 + j;
                out[go] = x[go] + g * acc[mt][nt][r];
            }
        }
}

// ---------------------------------------------------------------------------
extern "C" void kernel_launch(void* const* d_in, const int* in_sizes, int n_in,
                              void* d_out, int out_size, void* d_ws, size_t ws_size,
                              hipStream_t stream)
{
    const float* x     = (const float*)d_in[0];
    const float* W1    = (const float*)d_in[1];
    const float* W2    = (const float*)d_in[2];
    const float* gamma = (const float*)d_in[3];
    float* out = (float*)d_out;

    b16u* Qt = (b16u*)d_ws;                       // B*L*T bf16 = 2 MB
    b16u* Kt = Qt + (size_t)BB * LL * TT;         // 2 MB
    b16u* XT = Kt + (size_t)BB * LL * TT;         // B*C*L bf16 = 16.8 MB
    float* Mw = (float*)(XT + (size_t)BB * CC * LL);
    float* Zw = Mw + (size_t)BB * LL;             // total ~21 MB

    cvt_kernel<<<dim3(1024),           256, 0, stream>>>(x, XT);
    qk_kernel <<<dim3(LL / 64, BB),    256, 0, stream>>>(x, W1, W2, Qt, Kt);
    mz_kernel <<<dim3(LL / 64, BB),    256, 0, stream>>>(Qt, Kt, Mw, Zw);
    out_kernel<<<dim3(LL / 64, 2, BB), 256, 0, stream>>>(x, XT, Qt, Kt, Mw, Zw, gamma, out);
}